// Round 1
// baseline (2127.378 us; speedup 1.0000x reference)
//
#include <hip/hip_runtime.h>
#include <math.h>

#define T_TOK 2048
#define H_DIM 1024
#define E_NUM 64
#define KTOP 8
#define CAP  512
#define I_DIM 512
#define IS_DIM 2048

#define TM 64
#define TN 64
#define TK 16

__device__ __forceinline__ float sigm(float x){ return 1.f/(1.f+__expf(-x)); }

// ---------------- router + shared token gate + dispatch ----------------
__global__ __launch_bounds__(256)
void k_router(const float* __restrict__ X,
              const float* __restrict__ GW,     // [H,E]
              const float* __restrict__ SGW,    // [H]
              int* __restrict__ counts,
              int* __restrict__ etok,
              float* __restrict__ ew,
              float* __restrict__ gate_tok)
{
  const int t = blockIdx.x;
  const int tid = threadIdx.x;
  const float* xt = X + (size_t)t*H_DIM;
  __shared__ float logits[E_NUM];
  __shared__ float red[256];

  // logits: 4 partial h-groups per expert
  const int e = tid & 63;
  const int hi = tid >> 6;
  float acc = 0.f;
  for (int h = hi; h < H_DIM; h += 4)
    acc += xt[h]*GW[h*E_NUM + e];
  red[tid] = acc;
  __syncthreads();
  if (tid < 64) logits[tid] = red[tid] + red[tid+64] + red[tid+128] + red[tid+192];
  __syncthreads();

  // shared-expert token gate: sigmoid(x . SGW)
  float sacc = 0.f;
  for (int h = tid; h < H_DIM; h += 256) sacc += xt[h]*SGW[h];
  red[tid] = sacc;
  __syncthreads();
  for (int s = 128; s > 0; s >>= 1) {
    if (tid < s) red[tid] += red[tid+s];
    __syncthreads();
  }
  if (tid == 0) gate_tok[t] = sigm(red[0]);

  // top-8 of logits on wave 0; softmax over the 8 (global Z cancels in renorm)
  if (tid < 64) {
    float curv = logits[tid];
    int curi = tid;
    float topv[KTOP]; int topi[KTOP];
    #pragma unroll
    for (int r = 0; r < KTOP; ++r) {
      float bv = curv; int bi = curi;
      #pragma unroll
      for (int off = 32; off > 0; off >>= 1) {
        float ov = __shfl_xor(bv, off);
        int oi = __shfl_xor(bi, off);
        if (ov > bv || (ov == bv && oi < bi)) { bv = ov; bi = oi; }
      }
      topv[r] = bv; topi[r] = bi;
      if (curi == bi) curv = -INFINITY;
    }
    if (tid == 0) {
      float m = topv[0], s = 0.f, wv[KTOP];
      #pragma unroll
      for (int r = 0; r < KTOP; ++r){ wv[r] = __expf(topv[r]-m); s += wv[r]; }
      float inv = 1.f/s;
      for (int r = 0; r < KTOP; ++r) {
        int ee = topi[r];
        int pos = atomicAdd(&counts[ee], 1);
        if (pos < CAP) {
          etok[ee*CAP + pos] = t;
          ew[ee*CAP + pos] = wv[r]*inv;
        }
      }
    }
  }
}

// ---------------- shared expert: gate_up + SwiGLU -> ACT [T, IS] ----------------
__global__ __launch_bounds__(256)
void k_shared_gateup(const float* __restrict__ X,   // [T,H]
                     const float* __restrict__ W,   // [H, 2*IS]
                     float* __restrict__ ACT)       // [T, IS]
{
  __shared__ float As[TK][TM+4];
  __shared__ float B1s[TK][TN];
  __shared__ float B2s[TK][TN];
  const int tid = threadIdx.x;
  const int tx = tid & 15;
  const int ty = tid >> 4;
  const int n0 = blockIdx.x * TN;
  const int m0 = blockIdx.y * TM;
  const int ldb = 2*IS_DIM;

  float acc1[4][4] = {};
  float acc2[4][4] = {};

  const int ar = tid >> 2;            // 0..63
  const int ac4 = (tid & 3) * 4;      // 0,4,8,12
  const int bk = tid >> 4;            // 0..15
  const int bn = (tid & 15) * 4;

  for (int k0 = 0; k0 < H_DIM; k0 += TK) {
    float4 av = *(const float4*)(X + (size_t)(m0 + ar)*H_DIM + k0 + ac4);
    As[ac4+0][ar] = av.x; As[ac4+1][ar] = av.y; As[ac4+2][ar] = av.z; As[ac4+3][ar] = av.w;
    const float* bp = W + (size_t)(k0 + bk)*ldb + n0 + bn;
    *(float4*)&B1s[bk][bn] = *(const float4*)bp;
    *(float4*)&B2s[bk][bn] = *(const float4*)(bp + IS_DIM);
    __syncthreads();
    #pragma unroll
    for (int k = 0; k < TK; ++k) {
      float4 a  = *(const float4*)&As[k][ty*4];
      float4 b1 = *(const float4*)&B1s[k][tx*4];
      float4 b2 = *(const float4*)&B2s[k][tx*4];
      float avv[4] = {a.x,a.y,a.z,a.w};
      float b1v[4] = {b1.x,b1.y,b1.z,b1.w};
      float b2v[4] = {b2.x,b2.y,b2.z,b2.w};
      #pragma unroll
      for (int i = 0; i < 4; ++i)
        #pragma unroll
        for (int j = 0; j < 4; ++j) {
          acc1[i][j] += avv[i]*b1v[j];
          acc2[i][j] += avv[i]*b2v[j];
        }
    }
    __syncthreads();
  }
  #pragma unroll
  for (int i = 0; i < 4; ++i) {
    int m = m0 + ty*4 + i;
    float v[4];
    #pragma unroll
    for (int j = 0; j < 4; ++j) {
      float g = acc1[i][j];
      v[j] = g * sigm(g) * acc2[i][j];
    }
    float4 o; o.x=v[0]; o.y=v[1]; o.z=v[2]; o.w=v[3];
    *(float4*)(ACT + (size_t)m*IS_DIM + n0 + tx*4) = o;
  }
}

// ---------------- shared expert: down proj * token gate -> OUT (write) ----------------
__global__ __launch_bounds__(256)
void k_shared_down(const float* __restrict__ ACT,  // [T, IS]
                   const float* __restrict__ Wd,   // [IS, H]
                   const float* __restrict__ gate_tok,
                   float* __restrict__ OUT)        // [T, H]
{
  __shared__ float As[TK][TM+4];
  __shared__ float Bs[TK][TN];
  const int tid = threadIdx.x;
  const int tx = tid & 15;
  const int ty = tid >> 4;
  const int n0 = blockIdx.x * TN;
  const int m0 = blockIdx.y * TM;

  float acc[4][4] = {};
  const int ar = tid >> 2;
  const int ac4 = (tid & 3) * 4;
  const int bk = tid >> 4;
  const int bn = (tid & 15) * 4;

  for (int k0 = 0; k0 < IS_DIM; k0 += TK) {
    float4 av = *(const float4*)(ACT + (size_t)(m0 + ar)*IS_DIM + k0 + ac4);
    As[ac4+0][ar] = av.x; As[ac4+1][ar] = av.y; As[ac4+2][ar] = av.z; As[ac4+3][ar] = av.w;
    *(float4*)&Bs[bk][bn] = *(const float4*)(Wd + (size_t)(k0 + bk)*H_DIM + n0 + bn);
    __syncthreads();
    #pragma unroll
    for (int k = 0; k < TK; ++k) {
      float4 a = *(const float4*)&As[k][ty*4];
      float4 b = *(const float4*)&Bs[k][tx*4];
      float avv[4] = {a.x,a.y,a.z,a.w};
      float bv[4] = {b.x,b.y,b.z,b.w};
      #pragma unroll
      for (int i = 0; i < 4; ++i)
        #pragma unroll
        for (int j = 0; j < 4; ++j)
          acc[i][j] += avv[i]*bv[j];
    }
    __syncthreads();
  }
  #pragma unroll
  for (int i = 0; i < 4; ++i) {
    int m = m0 + ty*4 + i;
    float g = gate_tok[m];
    float4 o;
    o.x = acc[i][0]*g; o.y = acc[i][1]*g; o.z = acc[i][2]*g; o.w = acc[i][3]*g;
    *(float4*)(OUT + (size_t)m*H_DIM + n0 + tx*4) = o;
  }
}

// ---------------- expert gate_up + SwiGLU -> ACTG [16, CAP, I] ----------------
__global__ __launch_bounds__(256)
void k_expert_gateup(const float* __restrict__ X,     // [T,H]
                     const float* __restrict__ Wgu,   // [E,H,2I]
                     const int* __restrict__ counts,
                     const int* __restrict__ etok,
                     float* __restrict__ ACTG,        // [16, CAP, I]
                     int e_base)
{
  const int el = blockIdx.z;
  const int e  = e_base + el;
  int cnt = counts[e]; if (cnt > CAP) cnt = CAP;
  const int m0 = blockIdx.y * TM;
  if (m0 >= cnt) return;
  const int n0 = blockIdx.x * TN;   // within I

  __shared__ float As[TK][TM+4];
  __shared__ float B1s[TK][TN];
  __shared__ float B2s[TK][TN];
  const int tid = threadIdx.x;
  const int tx = tid & 15;
  const int ty = tid >> 4;

  float acc1[4][4] = {};
  float acc2[4][4] = {};

  const int ar = tid >> 2;
  const int ac4 = (tid & 3) * 4;
  const int bk = tid >> 4;
  const int bn = (tid & 15) * 4;
  const int row = m0 + ar;
  const int tok = (row < cnt) ? etok[e*CAP + row] : -1;
  const float* wbase = Wgu + (size_t)e*H_DIM*(2*I_DIM);

  for (int k0 = 0; k0 < H_DIM; k0 += TK) {
    float4 av = make_float4(0.f,0.f,0.f,0.f);
    if (tok >= 0) av = *(const float4*)(X + (size_t)tok*H_DIM + k0 + ac4);
    As[ac4+0][ar] = av.x; As[ac4+1][ar] = av.y; As[ac4+2][ar] = av.z; As[ac4+3][ar] = av.w;
    const float* bp = wbase + (size_t)(k0 + bk)*(2*I_DIM) + n0 + bn;
    *(float4*)&B1s[bk][bn] = *(const float4*)bp;
    *(float4*)&B2s[bk][bn] = *(const float4*)(bp + I_DIM);
    __syncthreads();
    #pragma unroll
    for (int k = 0; k < TK; ++k) {
      float4 a  = *(const float4*)&As[k][ty*4];
      float4 b1 = *(const float4*)&B1s[k][tx*4];
      float4 b2 = *(const float4*)&B2s[k][tx*4];
      float avv[4] = {a.x,a.y,a.z,a.w};
      float b1v[4] = {b1.x,b1.y,b1.z,b1.w};
      float b2v[4] = {b2.x,b2.y,b2.z,b2.w};
      #pragma unroll
      for (int i = 0; i < 4; ++i)
        #pragma unroll
        for (int j = 0; j < 4; ++j) {
          acc1[i][j] += avv[i]*b1v[j];
          acc2[i][j] += avv[i]*b2v[j];
        }
    }
    __syncthreads();
  }
  #pragma unroll
  for (int i = 0; i < 4; ++i) {
    int m = m0 + ty*4 + i;
    if (m < cnt) {
      float v[4];
      #pragma unroll
      for (int j = 0; j < 4; ++j) {
        float g = acc1[i][j];
        v[j] = g * sigm(g) * acc2[i][j];
      }
      float4 o; o.x=v[0]; o.y=v[1]; o.z=v[2]; o.w=v[3];
      *(float4*)(ACTG + ((size_t)el*CAP + m)*I_DIM + n0 + tx*4) = o;
    }
  }
}

// ---------------- expert down proj, scale by router weight, atomicAdd to OUT ----------------
__global__ __launch_bounds__(256)
void k_expert_down(const float* __restrict__ ACTG,   // [16, CAP, I]
                   const float* __restrict__ Wd,     // [E,I,H]
                   const int* __restrict__ counts,
                   const int* __restrict__ etok,
                   const float* __restrict__ ew,
                   float* __restrict__ OUT,          // [T,H]
                   int e_base)
{
  const int el = blockIdx.z;
  const int e  = e_base + el;
  int cnt = counts[e]; if (cnt > CAP) cnt = CAP;
  const int m0 = blockIdx.y * TM;
  if (m0 >= cnt) return;
  const int n0 = blockIdx.x * TN;

  __shared__ float As[TK][TM+4];
  __shared__ float Bs[TK][TN];
  const int tid = threadIdx.x;
  const int tx = tid & 15;
  const int ty = tid >> 4;

  float acc[4][4] = {};
  const int ar = tid >> 2;
  const int ac4 = (tid & 3) * 4;
  const int bk = tid >> 4;
  const int bn = (tid & 15) * 4;
  const int row = m0 + ar;
  const bool arow_ok = (row < cnt);
  const float* wbase = Wd + (size_t)e*I_DIM*H_DIM;

  for (int k0 = 0; k0 < I_DIM; k0 += TK) {
    float4 av = make_float4(0.f,0.f,0.f,0.f);
    if (arow_ok) av = *(const float4*)(ACTG + ((size_t)el*CAP + row)*I_DIM + k0 + ac4);
    As[ac4+0][ar] = av.x; As[ac4+1][ar] = av.y; As[ac4+2][ar] = av.z; As[ac4+3][ar] = av.w;
    *(float4*)&Bs[bk][bn] = *(const float4*)(wbase + (size_t)(k0 + bk)*H_DIM + n0 + bn);
    __syncthreads();
    #pragma unroll
    for (int k = 0; k < TK; ++k) {
      float4 a = *(const float4*)&As[k][ty*4];
      float4 b = *(const float4*)&Bs[k][tx*4];
      float avv[4] = {a.x,a.y,a.z,a.w};
      float bv[4] = {b.x,b.y,b.z,b.w};
      #pragma unroll
      for (int i = 0; i < 4; ++i)
        #pragma unroll
        for (int j = 0; j < 4; ++j)
          acc[i][j] += avv[i]*bv[j];
    }
    __syncthreads();
  }
  #pragma unroll
  for (int i = 0; i < 4; ++i) {
    int m = m0 + ty*4 + i;
    if (m < cnt) {
      float w = ew[e*CAP + m];
      int tok = etok[e*CAP + m];
      float* op = OUT + (size_t)tok*H_DIM + n0 + tx*4;
      #pragma unroll
      for (int j = 0; j < 4; ++j)
        atomicAdd(op + j, acc[i][j]*w);
    }
  }
}

extern "C" void kernel_launch(void* const* d_in, const int* in_sizes, int n_in,
                              void* d_out, int out_size, void* d_ws, size_t ws_size,
                              hipStream_t stream) {
  const float* x    = (const float*)d_in[0];   // [2,1024,1024] -> [T,H]
  const float* gw   = (const float*)d_in[1];   // [H,E]
  const float* sgw  = (const float*)d_in[2];   // [H,1]
  const float* sguw = (const float*)d_in[3];   // [H,2*Is]
  const float* sdw  = (const float*)d_in[4];   // [Is,H]
  const float* eguw = (const float*)d_in[5];   // [E,H,2I]
  const float* edw  = (const float*)d_in[6];   // [E,I,H]
  float* out = (float*)d_out;                  // [T,H]

  char* ws = (char*)d_ws;
  int*   counts   = (int*)(ws + 0);                    // 256 B
  int*   etok     = (int*)(ws + 4096);                 // 128 KB
  float* ew       = (float*)(ws + 4096 + 131072);      // 128 KB
  float* gate_tok = (float*)(ws + 4096 + 2*131072);    // 8 KB
  float* big      = (float*)(ws + (1u<<20));           // 16 MB, reused: ACT then ACTG groups

  hipMemsetAsync(counts, 0, E_NUM*sizeof(int), stream);
  k_router<<<T_TOK, 256, 0, stream>>>(x, gw, sgw, counts, etok, ew, gate_tok);
  k_shared_gateup<<<dim3(IS_DIM/TN, T_TOK/TM), 256, 0, stream>>>(x, sguw, big);
  k_shared_down<<<dim3(H_DIM/TN, T_TOK/TM), 256, 0, stream>>>(big, sdw, gate_tok, out);
  for (int g = 0; g < 4; ++g) {
    k_expert_gateup<<<dim3(I_DIM/TN, CAP/TM, 16), 256, 0, stream>>>(x, eguw, counts, etok, big, g*16);
    k_expert_down<<<dim3(H_DIM/TN, CAP/TM, 16), 256, 0, stream>>>(big, edw, counts, etok, ew, out, g*16);
  }
}

// Round 3
// 1374.883 us; speedup vs baseline: 1.5473x; 1.5473x over previous
//
#include <hip/hip_runtime.h>
#include <math.h>

#define T_TOK 2048
#define H_DIM 1024
#define E_NUM 64
#define KTOP 8
#define CAP  512
#define I_DIM 512
#define IS_DIM 2048

#define LDSTR 40   // padded LDS row stride in bf16 elems (80 B, 16B-aligned)

typedef __attribute__((ext_vector_type(8))) short short8;
typedef __attribute__((ext_vector_type(4))) float f32x4;

__device__ __forceinline__ float sigm(float x){ return 1.f/(1.f+__expf(-x)); }

// fp32 -> bf16 hi/lo split (truncation); hi+lo carries ~16 mantissa bits
__device__ __forceinline__ void split2(float x, unsigned short &h, unsigned short &l){
  unsigned int u = __float_as_uint(x);
  h = (unsigned short)(u >> 16);
  float hf = __uint_as_float(u & 0xFFFF0000u);
  l = (unsigned short)(__float_as_uint(x - hf) >> 16);
}

// ---------------- router + shared token gate + dispatch (unchanged, passes) ----------------
__global__ __launch_bounds__(256)
void k_router(const float* __restrict__ X,
              const float* __restrict__ GW,     // [H,E]
              const float* __restrict__ SGW,    // [H]
              int* __restrict__ counts,
              int* __restrict__ etok,
              float* __restrict__ ew,
              float* __restrict__ gate_tok)
{
  const int t = blockIdx.x;
  const int tid = threadIdx.x;
  const float* xt = X + (size_t)t*H_DIM;
  __shared__ float logits[E_NUM];
  __shared__ float red[256];

  const int e = tid & 63;
  const int hi = tid >> 6;
  float acc = 0.f;
  for (int h = hi; h < H_DIM; h += 4)
    acc += xt[h]*GW[h*E_NUM + e];
  red[tid] = acc;
  __syncthreads();
  if (tid < 64) logits[tid] = red[tid] + red[tid+64] + red[tid+128] + red[tid+192];
  __syncthreads();

  float sacc = 0.f;
  for (int h = tid; h < H_DIM; h += 256) sacc += xt[h]*SGW[h];
  red[tid] = sacc;
  __syncthreads();
  for (int s = 128; s > 0; s >>= 1) {
    if (tid < s) red[tid] += red[tid+s];
    __syncthreads();
  }
  if (tid == 0) gate_tok[t] = sigm(red[0]);

  if (tid < 64) {
    float curv = logits[tid];
    int curi = tid;
    float topv[KTOP]; int topi[KTOP];
    #pragma unroll
    for (int r = 0; r < KTOP; ++r) {
      float bv = curv; int bi = curi;
      #pragma unroll
      for (int off = 32; off > 0; off >>= 1) {
        float ov = __shfl_xor(bv, off);
        int oi = __shfl_xor(bi, off);
        if (ov > bv || (ov == bv && oi < bi)) { bv = ov; bi = oi; }
      }
      topv[r] = bv; topi[r] = bi;
      if (curi == bi) curv = -INFINITY;
    }
    if (tid == 0) {
      float m = topv[0], s = 0.f, wv[KTOP];
      #pragma unroll
      for (int r = 0; r < KTOP; ++r){ wv[r] = __expf(topv[r]-m); s += wv[r]; }
      float inv = 1.f/s;
      for (int r = 0; r < KTOP; ++r) {
        int ee = topi[r];
        int pos = atomicAdd(&counts[ee], 1);
        if (pos < CAP) {
          etok[ee*CAP + pos] = t;
          ew[ee*CAP + pos] = wv[r]*inv;
        }
      }
    }
  }
}

// ---------------- MFMA engine helpers ----------------

// stage B tile [32k x 128n] (fp32, row-major [K,N]) -> LDS transposed [n][k] hi/lo,
// chunk-XOR swizzled: logical 8-elem k-chunk c stored at c ^ ((n>>3)&3)
__device__ __forceinline__ void stage_B(const float* __restrict__ B, int ldb,
                                        int c0, int c1,
                                        unsigned short* Bh, unsigned short* Bl, int tid)
{
  #pragma unroll
  for (int i = 0; i < 4; ++i) {
    int id = tid + i*256;
    int n  = id & 127;
    int q2 = id >> 7;                       // k-subgroup of 4
    int col = (n < 64) ? (c0 + n) : (c1 + (n - 64));
    const float* p = B + (size_t)(q2*4)*ldb + col;
    float v0 = p[0], v1 = p[ldb], v2 = p[2*ldb], v3 = p[3*ldb];
    unsigned short h0,h1,h2,h3,l0,l1,l2,l3;
    split2(v0,h0,l0); split2(v1,h1,l1); split2(v2,h2,l2); split2(v3,h3,l3);
    int off = n*LDSTR + (((q2>>1) ^ ((n>>3)&3))*8) + (q2&1)*4;
    *(ushort4*)(Bh + off) = make_ushort4(h0,h1,h2,h3);
    *(ushort4*)(Bl + off) = make_ushort4(l0,l1,l2,l3);
  }
}

// one k32 step: 48 MFMA per wave (3 split passes x 4m x 4n), acc[mt][nt]
__device__ __forceinline__ void mfma_tiles(const unsigned short* Ah, const unsigned short* Al,
                                           const unsigned short* Bh, const unsigned short* Bl,
                                           int wy, const int* bidx, int lane, f32x4 acc[4][4])
{
  const int lm = lane & 15, q = lane >> 4;
  short8 ah[4], al[4];
  #pragma unroll
  for (int mt = 0; mt < 4; ++mt) {
    int off = (wy*64 + mt*16 + lm)*LDSTR + q*8;
    ah[mt] = *(const short8*)(Ah + off);
    al[mt] = *(const short8*)(Al + off);
  }
  #pragma unroll
  for (int nt = 0; nt < 4; ++nt) {
    int n = bidx[nt]*16 + lm;
    int off = n*LDSTR + ((q ^ ((n>>3)&3))*8);
    short8 bh = *(const short8*)(Bh + off);
    short8 bl = *(const short8*)(Bl + off);
    #pragma unroll
    for (int mt = 0; mt < 4; ++mt) {
      acc[mt][nt] = __builtin_amdgcn_mfma_f32_16x16x32_bf16(ah[mt], bh, acc[mt][nt], 0,0,0);
      acc[mt][nt] = __builtin_amdgcn_mfma_f32_16x16x32_bf16(ah[mt], bl, acc[mt][nt], 0,0,0);
      acc[mt][nt] = __builtin_amdgcn_mfma_f32_16x16x32_bf16(al[mt], bh, acc[mt][nt], 0,0,0);
    }
  }
}

#define DECL_LDS \
  __shared__ __align__(16) unsigned short Ah[128*LDSTR]; \
  __shared__ __align__(16) unsigned short Al[128*LDSTR]; \
  __shared__ __align__(16) unsigned short Bh[128*LDSTR]; \
  __shared__ __align__(16) unsigned short Bl[128*LDSTR];

#define ZERO_ACC \
  f32x4 acc[4][4]; \
  _Pragma("unroll") for (int a_=0;a_<4;++a_) _Pragma("unroll") for (int b_=0;b_<4;++b_) \
    acc[a_][b_] = (f32x4){0.f,0.f,0.f,0.f};

// ---------------- shared gate_up + SwiGLU -> ACT hi/lo planes [T, IS] ----------------
__global__ __launch_bounds__(256,2)
void k_gu_shared(const float* __restrict__ X, const float* __restrict__ W,
                 unsigned short* __restrict__ Oh, unsigned short* __restrict__ Ol)
{
  DECL_LDS
  const int tid = threadIdx.x, lane = tid & 63, wave = tid >> 6;
  const int wx = wave & 1, wy = wave >> 1;
  const int m0 = blockIdx.y * 128;
  const int gn0 = blockIdx.x * 64;
  ZERO_ACC
  const int bidx[4] = {2*wx, 2*wx+1, 4+2*wx, 5+2*wx};

  for (int k0 = 0; k0 < H_DIM; k0 += 32) {
    #pragma unroll
    for (int i = 0; i < 4; ++i) {
      int id = tid + i*256;
      int row = id >> 3, kc = (id & 7)*4;
      float4 v = *(const float4*)(X + (size_t)(m0+row)*H_DIM + k0 + kc);
      unsigned short h0,h1,h2,h3,l0,l1,l2,l3;
      split2(v.x,h0,l0); split2(v.y,h1,l1); split2(v.z,h2,l2); split2(v.w,h3,l3);
      int off = row*LDSTR + kc;
      *(ushort4*)(Ah + off) = make_ushort4(h0,h1,h2,h3);
      *(ushort4*)(Al + off) = make_ushort4(l0,l1,l2,l3);
    }
    stage_B(W + (size_t)k0*(2*IS_DIM), 2*IS_DIM, gn0, IS_DIM + gn0, Bh, Bl, tid);
    __syncthreads();
    mfma_tiles(Ah, Al, Bh, Bl, wy, bidx, lane, acc);
    __syncthreads();
  }
  const int lm = lane & 15, q = lane >> 4;
  #pragma unroll
  for (int mt = 0; mt < 4; ++mt) {
    int m = m0 + wy*64 + mt*16 + q*4;
    #pragma unroll
    for (int jj = 0; jj < 2; ++jj) {
      int col = gn0 + (2*wx + jj)*16 + lm;
      #pragma unroll
      for (int r = 0; r < 4; ++r) {
        float g = acc[mt][jj][r], u = acc[mt][2+jj][r];
        float a = g * sigm(g) * u;
        unsigned short h,l; split2(a,h,l);
        size_t o = (size_t)(m + r)*IS_DIM + col;
        Oh[o] = h; Ol[o] = l;
      }
    }
  }
}

// ---------------- shared down proj * token gate -> OUT ----------------
__global__ __launch_bounds__(256,2)
void k_dn_shared(const unsigned short* __restrict__ Sh, const unsigned short* __restrict__ Sl,
                 const float* __restrict__ W, const float* __restrict__ gate_tok,
                 float* __restrict__ OUT)
{
  DECL_LDS
  const int tid = threadIdx.x, lane = tid & 63, wave = tid >> 6;
  const int wx = wave & 1, wy = wave >> 1;
  const int m0 = blockIdx.y * 128;
  const int n0 = blockIdx.x * 128;
  ZERO_ACC
  const int bidx[4] = {4*wx, 4*wx+1, 4*wx+2, 4*wx+3};

  for (int k0 = 0; k0 < IS_DIM; k0 += 32) {
    #pragma unroll
    for (int i = 0; i < 2; ++i) {
      int id = tid + i*256;
      int row = id >> 2, kc8 = (id & 3)*8;
      size_t go = (size_t)(m0+row)*IS_DIM + k0 + kc8;
      int off = row*LDSTR + kc8;
      *(uint4*)(Ah + off) = *(const uint4*)(Sh + go);
      *(uint4*)(Al + off) = *(const uint4*)(Sl + go);
    }
    stage_B(W + (size_t)k0*H_DIM, H_DIM, n0, n0 + 64, Bh, Bl, tid);
    __syncthreads();
    mfma_tiles(Ah, Al, Bh, Bl, wy, bidx, lane, acc);
    __syncthreads();
  }
  const int lm = lane & 15, q = lane >> 4;
  #pragma unroll
  for (int mt = 0; mt < 4; ++mt) {
    int m = m0 + wy*64 + mt*16 + q*4;
    #pragma unroll
    for (int r = 0; r < 4; ++r) {
      float gt = gate_tok[m + r];
      #pragma unroll
      for (int nt = 0; nt < 4; ++nt) {
        int col = n0 + wx*64 + nt*16 + lm;
        OUT[(size_t)(m + r)*H_DIM + col] = acc[mt][nt][r] * gt;
      }
    }
  }
}

// ---------------- expert gate_up + SwiGLU -> ACTG hi/lo [16, CAP, I] ----------------
__global__ __launch_bounds__(256,2)
void k_gu_expert(const float* __restrict__ X, const float* __restrict__ Wgu,
                 const int* __restrict__ counts, const int* __restrict__ etok,
                 unsigned short* __restrict__ Oh, unsigned short* __restrict__ Ol,
                 int e_base)
{
  const int el = blockIdx.z, e = e_base + el;
  int cnt = counts[e]; if (cnt > CAP) cnt = CAP;
  const int m0 = blockIdx.y * 128;
  if (m0 >= cnt) return;
  const int gn0 = blockIdx.x * 64;
  DECL_LDS
  const int tid = threadIdx.x, lane = tid & 63, wave = tid >> 6;
  const int wx = wave & 1, wy = wave >> 1;
  ZERO_ACC
  const int bidx[4] = {2*wx, 2*wx+1, 4+2*wx, 5+2*wx};
  const float* Wb = Wgu + (size_t)e*H_DIM*(2*I_DIM);

  int tokr[4];
  #pragma unroll
  for (int i = 0; i < 4; ++i) {
    int m = m0 + ((tid + i*256) >> 3);
    tokr[i] = (m < cnt) ? etok[e*CAP + m] : -1;
  }

  for (int k0 = 0; k0 < H_DIM; k0 += 32) {
    #pragma unroll
    for (int i = 0; i < 4; ++i) {
      int id = tid + i*256;
      int row = id >> 3, kc = (id & 7)*4;
      float4 v = make_float4(0.f,0.f,0.f,0.f);
      if (tokr[i] >= 0) v = *(const float4*)(X + (size_t)tokr[i]*H_DIM + k0 + kc);
      unsigned short h0,h1,h2,h3,l0,l1,l2,l3;
      split2(v.x,h0,l0); split2(v.y,h1,l1); split2(v.z,h2,l2); split2(v.w,h3,l3);
      int off = row*LDSTR + kc;
      *(ushort4*)(Ah + off) = make_ushort4(h0,h1,h2,h3);
      *(ushort4*)(Al + off) = make_ushort4(l0,l1,l2,l3);
    }
    stage_B(Wb + (size_t)k0*(2*I_DIM), 2*I_DIM, gn0, I_DIM + gn0, Bh, Bl, tid);
    __syncthreads();
    mfma_tiles(Ah, Al, Bh, Bl, wy, bidx, lane, acc);
    __syncthreads();
  }
  const int lm = lane & 15, q = lane >> 4;
  #pragma unroll
  for (int mt = 0; mt < 4; ++mt) {
    int m = m0 + wy*64 + mt*16 + q*4;
    #pragma unroll
    for (int jj = 0; jj < 2; ++jj) {
      int col = gn0 + (2*wx + jj)*16 + lm;
      #pragma unroll
      for (int r = 0; r < 4; ++r) {
        if (m + r < cnt) {
          float g = acc[mt][jj][r], u = acc[mt][2+jj][r];
          float a = g * sigm(g) * u;
          unsigned short h,l; split2(a,h,l);
          size_t o = ((size_t)el*CAP + m + r)*I_DIM + col;
          Oh[o] = h; Ol[o] = l;
        }
      }
    }
  }
}

// ---------------- expert down proj -> atomicAdd into OUT ----------------
__global__ __launch_bounds__(256,2)
void k_dn_expert(const unsigned short* __restrict__ Gh, const unsigned short* __restrict__ Gl,
                 const float* __restrict__ Wd,
                 const int* __restrict__ counts, const int* __restrict__ etok,
                 const float* __restrict__ ew, float* __restrict__ OUT, int e_base)
{
  const int el = blockIdx.z, e = e_base + el;
  int cnt = counts[e]; if (cnt > CAP) cnt = CAP;
  const int m0 = blockIdx.y * 128;
  if (m0 >= cnt) return;
  const int n0 = blockIdx.x * 128;
  DECL_LDS
  const int tid = threadIdx.x, lane = tid & 63, wave = tid >> 6;
  const int wx = wave & 1, wy = wave >> 1;
  ZERO_ACC
  const int bidx[4] = {4*wx, 4*wx+1, 4*wx+2, 4*wx+3};
  const float* Wb = Wd + (size_t)e*I_DIM*H_DIM;

  for (int k0 = 0; k0 < I_DIM; k0 += 32) {
    #pragma unroll
    for (int i = 0; i < 2; ++i) {
      int id = tid + i*256;
      int row = id >> 2, kc8 = (id & 3)*8;
      uint4 hv = make_uint4(0,0,0,0), lv = make_uint4(0,0,0,0);
      if (m0 + row < cnt) {
        size_t go = ((size_t)el*CAP + m0 + row)*I_DIM + k0 + kc8;
        hv = *(const uint4*)(Gh + go);
        lv = *(const uint4*)(Gl + go);
      }
      int off = row*LDSTR + kc8;
      *(uint4*)(Ah + off) = hv;
      *(uint4*)(Al + off) = lv;
    }
    stage_B(Wb + (size_t)k0*H_DIM, H_DIM, n0, n0 + 64, Bh, Bl, tid);
    __syncthreads();
    mfma_tiles(Ah, Al, Bh, Bl, wy, bidx, lane, acc);
    __syncthreads();
  }
  const int lm = lane & 15, q = lane >> 4;
  #pragma unroll
  for (int mt = 0; mt < 4; ++mt) {
    int m = m0 + wy*64 + mt*16 + q*4;
    #pragma unroll
    for (int r = 0; r < 4; ++r) {
      if (m + r < cnt) {
        float w = ew[e*CAP + m + r];
        int tok = etok[e*CAP + m + r];
        float* op = OUT + (size_t)tok*H_DIM;
        #pragma unroll
        for (int nt = 0; nt < 4; ++nt) {
          int col = n0 + wx*64 + nt*16 + lm;
          atomicAdd(op + col, acc[mt][nt][r] * w);
        }
      }
    }
  }
}

extern "C" void kernel_launch(void* const* d_in, const int* in_sizes, int n_in,
                              void* d_out, int out_size, void* d_ws, size_t ws_size,
                              hipStream_t stream) {
  const float* x    = (const float*)d_in[0];   // [T,H]
  const float* gw   = (const float*)d_in[1];   // [H,E]
  const float* sgw  = (const float*)d_in[2];   // [H,1]
  const float* sguw = (const float*)d_in[3];   // [H,2*Is]
  const float* sdw  = (const float*)d_in[4];   // [Is,H]
  const float* eguw = (const float*)d_in[5];   // [E,H,2I]
  const float* edw  = (const float*)d_in[6];   // [E,I,H]
  float* out = (float*)d_out;                  // [T,H]

  char* ws = (char*)d_ws;
  int*   counts   = (int*)(ws + 0);
  int*   etok     = (int*)(ws + 4096);
  float* ew       = (float*)(ws + 4096 + 131072);
  float* gate_tok = (float*)(ws + 4096 + 2*131072);
  // bf16 hi/lo activation planes (8 MiB each), reused shared ACT -> expert ACTG
  unsigned short* Ph = (unsigned short*)(ws + (1u<<20));
  unsigned short* Pl = (unsigned short*)(ws + (9u<<20));

  hipMemsetAsync(counts, 0, E_NUM*sizeof(int), stream);
  k_router<<<T_TOK, 256, 0, stream>>>(x, gw, sgw, counts, etok, ew, gate_tok);
  k_gu_shared<<<dim3(IS_DIM/64, T_TOK/128), 256, 0, stream>>>(x, sguw, Ph, Pl);
  k_dn_shared<<<dim3(H_DIM/128, T_TOK/128), 256, 0, stream>>>(Ph, Pl, sdw, gate_tok, out);
  for (int g = 0; g < 4; ++g) {
    k_gu_expert<<<dim3(I_DIM/64, CAP/128, 16), 256, 0, stream>>>(x, eguw, counts, etok, Ph, Pl, g*16);
    k_dn_expert<<<dim3(H_DIM/128, CAP/128, 16), 256, 0, stream>>>(Ph, Pl, edw, counts, etok, ew, out, g*16);
  }
}

// Round 4
// 1178.980 us; speedup vs baseline: 1.8044x; 1.1662x over previous
//
#include <hip/hip_runtime.h>
#include <math.h>

#define T_TOK 2048
#define H_DIM 1024
#define E_NUM 64
#define KTOP 8
#define CAP  512
#define I_DIM 512
#define IS_DIM 2048

#define LDSTR 40   // padded LDS row stride in fp16 elems (80 B, 16B-aligned)

typedef __attribute__((ext_vector_type(8))) _Float16 half8;
typedef __attribute__((ext_vector_type(4))) _Float16 half4v;
typedef __attribute__((ext_vector_type(4))) float f32x4;

__device__ __forceinline__ float sigm(float x){ return 1.f/(1.f+__expf(-x)); }

// ---------------- router part 1: logits = X @ GW (fp32, exact routing) + token gate ----------------
__global__ __launch_bounds__(256)
void k_logits(const float* __restrict__ X, const float* __restrict__ GW,
              const float* __restrict__ SGW, float* __restrict__ logits,
              float* __restrict__ gate_tok)
{
  __shared__ float Xs[32*33];
  __shared__ float Ws[32*64];
  __shared__ float SGWs[32];
  __shared__ float red[256];
  const int tid = threadIdx.x;
  const int t0 = blockIdx.x * 32;
  const int tx = tid & 15, ty = tid >> 4;
  const int tg = tid & 31, qq = tid >> 5;
  float acc[2][4] = {};
  float gacc = 0.f;

  for (int k0 = 0; k0 < H_DIM; k0 += 32) {
    { // stage X 32x32
      int row = tid >> 3, c4 = (tid & 7)*4;
      float4 v = *(const float4*)(X + (size_t)(t0+row)*H_DIM + k0 + c4);
      Xs[row*33+c4+0]=v.x; Xs[row*33+c4+1]=v.y; Xs[row*33+c4+2]=v.z; Xs[row*33+c4+3]=v.w;
    }
    #pragma unroll
    for (int i=0;i<2;++i){ // stage W 32x64
      int id = tid + i*256;
      int kk = id >> 4, c4 = (id & 15)*4;
      *(float4*)(Ws + kk*64 + c4) = *(const float4*)(GW + (size_t)(k0+kk)*E_NUM + c4);
    }
    if (tid < 32) SGWs[tid] = SGW[k0 + tid];
    __syncthreads();
    #pragma unroll 8
    for (int k=0;k<32;++k){
      float b[4];
      #pragma unroll
      for(int j=0;j<4;++j) b[j] = Ws[k*64 + tx*4 + j];
      #pragma unroll
      for(int i=0;i<2;++i){
        float a = Xs[(ty*2+i)*33 + k];
        #pragma unroll
        for(int j=0;j<4;++j) acc[i][j] = fmaf(a, b[j], acc[i][j]);
      }
    }
    #pragma unroll
    for (int k=0;k<4;++k)
      gacc = fmaf(Xs[tg*33 + qq*4 + k], SGWs[qq*4+k], gacc);
    __syncthreads();
  }
  #pragma unroll
  for(int i=0;i<2;++i){
    float4 o = {acc[i][0],acc[i][1],acc[i][2],acc[i][3]};
    *(float4*)(logits + (size_t)(t0+ty*2+i)*E_NUM + tx*4) = o;
  }
  red[tid] = gacc; __syncthreads();
  if (tid < 32) {
    float g = 0.f;
    #pragma unroll
    for (int p=0;p<8;++p) g += red[tid + p*32];
    gate_tok[t0+tid] = sigm(g);
  }
}

// ---------------- router part 2: top-8 + softmax-renorm + dispatch ----------------
__global__ __launch_bounds__(256)
void k_topk(const float* __restrict__ logits,
            int* __restrict__ counts, int* __restrict__ etok, float* __restrict__ ew)
{
  const int tid = threadIdx.x;
  const int lane = tid & 63, w = tid >> 6;
  const int t = blockIdx.x*4 + w;
  float curv = logits[(size_t)t*E_NUM + lane];
  int curi = lane;
  float topv[KTOP]; int topi[KTOP];
  #pragma unroll
  for (int r = 0; r < KTOP; ++r) {
    float bv = curv; int bi = curi;
    #pragma unroll
    for (int off = 32; off > 0; off >>= 1) {
      float ov = __shfl_xor(bv, off);
      int oi = __shfl_xor(bi, off);
      if (ov > bv || (ov == bv && oi < bi)) { bv = ov; bi = oi; }
    }
    topv[r] = bv; topi[r] = bi;
    if (curi == bi) curv = -INFINITY;
  }
  if (lane == 0) {
    float m = topv[0], s = 0.f, wv[KTOP];
    #pragma unroll
    for (int r = 0; r < KTOP; ++r){ wv[r] = __expf(topv[r]-m); s += wv[r]; }
    float inv = 1.f/s;
    for (int r = 0; r < KTOP; ++r) {
      int ee = topi[r];
      int pos = atomicAdd(&counts[ee], 1);
      if (pos < CAP) {
        etok[ee*CAP + pos] = t;
        ew[ee*CAP + pos] = wv[r]*inv;
      }
    }
  }
}

// ---------------- MFMA engine helpers (fp16 single-pass) ----------------

// stage B tile [32k x 128n] (fp32 row-major [K,N]) -> LDS transposed [n][k] fp16,
// chunk-XOR swizzled: logical 8-elem k-chunk c stored at c ^ ((n>>3)&3)
__device__ __forceinline__ void stage_B_h(const float* __restrict__ B, int ldb,
                                          int c0, int c1, _Float16* Bs, int tid)
{
  #pragma unroll
  for (int i = 0; i < 4; ++i) {
    int id = tid + i*256;
    int n  = id & 127;
    int q2 = id >> 7;                       // 0..7, k rows q2*4..q2*4+3
    int col = (n < 64) ? (c0 + n) : (c1 + (n - 64));
    const float* p = B + (size_t)(q2*4)*ldb + col;
    float v0 = p[0], v1 = p[ldb], v2 = p[2*ldb], v3 = p[3*ldb];
    half4v hv = { (_Float16)v0, (_Float16)v1, (_Float16)v2, (_Float16)v3 };
    int off = n*LDSTR + (((q2>>1) ^ ((n>>3)&3))*8) + (q2&1)*4;
    *(half4v*)(Bs + off) = hv;
  }
}

// one k32 step: 16 MFMA per wave (4m x 4n)
__device__ __forceinline__ void mfma_tiles_h(const _Float16* As, const _Float16* Bs,
                                             int wy, const int* bidx, int lane, f32x4 acc[4][4])
{
  const int lm = lane & 15, q = lane >> 4;
  half8 a[4];
  #pragma unroll
  for (int mt = 0; mt < 4; ++mt)
    a[mt] = *(const half8*)(As + (wy*64 + mt*16 + lm)*LDSTR + q*8);
  #pragma unroll
  for (int nt = 0; nt < 4; ++nt) {
    int n = bidx[nt]*16 + lm;
    half8 b = *(const half8*)(Bs + n*LDSTR + ((q ^ ((n>>3)&3))*8));
    #pragma unroll
    for (int mt = 0; mt < 4; ++mt)
      acc[mt][nt] = __builtin_amdgcn_mfma_f32_16x16x32_f16(a[mt], b, acc[mt][nt], 0,0,0);
  }
}

#define DECL_LDS \
  __shared__ __align__(16) _Float16 As[128*LDSTR]; \
  __shared__ __align__(16) _Float16 Bs[128*LDSTR];

#define ZERO_ACC \
  f32x4 acc[4][4]; \
  _Pragma("unroll") for (int a_=0;a_<4;++a_) _Pragma("unroll") for (int b_=0;b_<4;++b_) \
    acc[a_][b_] = (f32x4){0.f,0.f,0.f,0.f};

// ---------------- shared gate_up + SwiGLU -> ACT fp16 [T, IS] ----------------
__global__ __launch_bounds__(256,3)
void k_gu_shared(const float* __restrict__ X, const float* __restrict__ W,
                 _Float16* __restrict__ O)
{
  DECL_LDS
  const int tid = threadIdx.x, lane = tid & 63, wave = tid >> 6;
  const int wx = wave & 1, wy = wave >> 1;
  const int m0 = blockIdx.y * 128;
  const int gn0 = blockIdx.x * 64;
  ZERO_ACC
  const int bidx[4] = {2*wx, 2*wx+1, 4+2*wx, 5+2*wx};

  for (int k0 = 0; k0 < H_DIM; k0 += 32) {
    #pragma unroll
    for (int i = 0; i < 4; ++i) {
      int id = tid + i*256;
      int row = id >> 3, kc = (id & 7)*4;
      float4 v = *(const float4*)(X + (size_t)(m0+row)*H_DIM + k0 + kc);
      half4v hv = { (_Float16)v.x, (_Float16)v.y, (_Float16)v.z, (_Float16)v.w };
      *(half4v*)(As + row*LDSTR + kc) = hv;
    }
    stage_B_h(W + (size_t)k0*(2*IS_DIM), 2*IS_DIM, gn0, IS_DIM + gn0, Bs, tid);
    __syncthreads();
    mfma_tiles_h(As, Bs, wy, bidx, lane, acc);
    __syncthreads();
  }
  const int lm = lane & 15, q = lane >> 4;
  #pragma unroll
  for (int mt = 0; mt < 4; ++mt) {
    int m = m0 + wy*64 + mt*16 + q*4;
    #pragma unroll
    for (int jj = 0; jj < 2; ++jj) {
      int col = gn0 + (2*wx + jj)*16 + lm;
      #pragma unroll
      for (int r = 0; r < 4; ++r) {
        float g = acc[mt][jj][r], u = acc[mt][2+jj][r];
        O[(size_t)(m + r)*IS_DIM + col] = (_Float16)(g * sigm(g) * u);
      }
    }
  }
}

// ---------------- shared down proj * token gate -> OUT ----------------
__global__ __launch_bounds__(256,3)
void k_dn_shared(const _Float16* __restrict__ S, const float* __restrict__ W,
                 const float* __restrict__ gate_tok, float* __restrict__ OUT)
{
  DECL_LDS
  const int tid = threadIdx.x, lane = tid & 63, wave = tid >> 6;
  const int wx = wave & 1, wy = wave >> 1;
  const int m0 = blockIdx.y * 128;
  const int n0 = blockIdx.x * 128;
  ZERO_ACC
  const int bidx[4] = {4*wx, 4*wx+1, 4*wx+2, 4*wx+3};

  for (int k0 = 0; k0 < IS_DIM; k0 += 32) {
    #pragma unroll
    for (int i = 0; i < 2; ++i) {
      int id = tid + i*256;
      int row = id >> 2, kc8 = (id & 3)*8;
      *(half8*)(As + row*LDSTR + kc8) =
        *(const half8*)(S + (size_t)(m0+row)*IS_DIM + k0 + kc8);
    }
    stage_B_h(W + (size_t)k0*H_DIM, H_DIM, n0, n0 + 64, Bs, tid);
    __syncthreads();
    mfma_tiles_h(As, Bs, wy, bidx, lane, acc);
    __syncthreads();
  }
  const int lm = lane & 15, q = lane >> 4;
  #pragma unroll
  for (int mt = 0; mt < 4; ++mt) {
    int m = m0 + wy*64 + mt*16 + q*4;
    #pragma unroll
    for (int r = 0; r < 4; ++r) {
      float gt = gate_tok[m + r];
      #pragma unroll
      for (int nt = 0; nt < 4; ++nt) {
        int col = n0 + wx*64 + nt*16 + lm;
        OUT[(size_t)(m + r)*H_DIM + col] = acc[mt][nt][r] * gt;
      }
    }
  }
}

// ---------------- expert gate_up + SwiGLU -> ACTG fp16 [16, CAP, I] ----------------
__global__ __launch_bounds__(256,3)
void k_gu_expert(const float* __restrict__ X, const float* __restrict__ Wgu,
                 const int* __restrict__ counts, const int* __restrict__ etok,
                 _Float16* __restrict__ O, int e_base)
{
  const int el = blockIdx.z, e = e_base + el;
  int cnt = counts[e]; if (cnt > CAP) cnt = CAP;
  const int m0 = blockIdx.y * 128;
  if (m0 >= cnt) return;
  const int gn0 = blockIdx.x * 64;
  DECL_LDS
  const int tid = threadIdx.x, lane = tid & 63, wave = tid >> 6;
  const int wx = wave & 1, wy = wave >> 1;
  ZERO_ACC
  const int bidx[4] = {2*wx, 2*wx+1, 4+2*wx, 5+2*wx};
  const float* Wb = Wgu + (size_t)e*H_DIM*(2*I_DIM);

  int tokr[4];
  #pragma unroll
  for (int i = 0; i < 4; ++i) {
    int m = m0 + ((tid + i*256) >> 3);
    tokr[i] = (m < cnt) ? etok[e*CAP + m] : -1;
  }

  for (int k0 = 0; k0 < H_DIM; k0 += 32) {
    #pragma unroll
    for (int i = 0; i < 4; ++i) {
      int id = tid + i*256;
      int row = id >> 3, kc = (id & 7)*4;
      float4 v = make_float4(0.f,0.f,0.f,0.f);
      if (tokr[i] >= 0) v = *(const float4*)(X + (size_t)tokr[i]*H_DIM + k0 + kc);
      half4v hv = { (_Float16)v.x, (_Float16)v.y, (_Float16)v.z, (_Float16)v.w };
      *(half4v*)(As + row*LDSTR + kc) = hv;
    }
    stage_B_h(Wb + (size_t)k0*(2*I_DIM), 2*I_DIM, gn0, I_DIM + gn0, Bs, tid);
    __syncthreads();
    mfma_tiles_h(As, Bs, wy, bidx, lane, acc);
    __syncthreads();
  }
  const int lm = lane & 15, q = lane >> 4;
  #pragma unroll
  for (int mt = 0; mt < 4; ++mt) {
    int m = m0 + wy*64 + mt*16 + q*4;
    #pragma unroll
    for (int jj = 0; jj < 2; ++jj) {
      int col = gn0 + (2*wx + jj)*16 + lm;
      #pragma unroll
      for (int r = 0; r < 4; ++r) {
        if (m + r < cnt) {
          float g = acc[mt][jj][r], u = acc[mt][2+jj][r];
          O[((size_t)el*CAP + m + r)*I_DIM + col] = (_Float16)(g * sigm(g) * u);
        }
      }
    }
  }
}

// ---------------- expert down proj -> atomicAdd into OUT ----------------
__global__ __launch_bounds__(256,3)
void k_dn_expert(const _Float16* __restrict__ G, const float* __restrict__ Wd,
                 const int* __restrict__ counts, const int* __restrict__ etok,
                 const float* __restrict__ ew, float* __restrict__ OUT, int e_base)
{
  const int el = blockIdx.z, e = e_base + el;
  int cnt = counts[e]; if (cnt > CAP) cnt = CAP;
  const int m0 = blockIdx.y * 128;
  if (m0 >= cnt) return;
  const int n0 = blockIdx.x * 128;
  DECL_LDS
  const int tid = threadIdx.x, lane = tid & 63, wave = tid >> 6;
  const int wx = wave & 1, wy = wave >> 1;
  ZERO_ACC
  const int bidx[4] = {4*wx, 4*wx+1, 4*wx+2, 4*wx+3};
  const float* Wb = Wd + (size_t)e*I_DIM*H_DIM;

  for (int k0 = 0; k0 < I_DIM; k0 += 32) {
    #pragma unroll
    for (int i = 0; i < 2; ++i) {
      int id = tid + i*256;
      int row = id >> 2, kc8 = (id & 3)*8;
      half8 hv = {0,0,0,0,0,0,0,0};
      if (m0 + row < cnt)
        hv = *(const half8*)(G + ((size_t)el*CAP + m0 + row)*I_DIM + k0 + kc8);
      *(half8*)(As + row*LDSTR + kc8) = hv;
    }
    stage_B_h(Wb + (size_t)k0*H_DIM, H_DIM, n0, n0 + 64, Bs, tid);
    __syncthreads();
    mfma_tiles_h(As, Bs, wy, bidx, lane, acc);
    __syncthreads();
  }
  const int lm = lane & 15, q = lane >> 4;
  #pragma unroll
  for (int mt = 0; mt < 4; ++mt) {
    int m = m0 + wy*64 + mt*16 + q*4;
    #pragma unroll
    for (int r = 0; r < 4; ++r) {
      if (m + r < cnt) {
        float w = ew[e*CAP + m + r];
        int tok = etok[e*CAP + m + r];
        float* op = OUT + (size_t)tok*H_DIM;
        #pragma unroll
        for (int nt = 0; nt < 4; ++nt) {
          int col = n0 + wx*64 + nt*16 + lm;
          atomicAdd(op + col, acc[mt][nt][r] * w);
        }
      }
    }
  }
}

extern "C" void kernel_launch(void* const* d_in, const int* in_sizes, int n_in,
                              void* d_out, int out_size, void* d_ws, size_t ws_size,
                              hipStream_t stream) {
  const float* x    = (const float*)d_in[0];   // [T,H]
  const float* gw   = (const float*)d_in[1];   // [H,E]
  const float* sgw  = (const float*)d_in[2];   // [H,1]
  const float* sguw = (const float*)d_in[3];   // [H,2*Is]
  const float* sdw  = (const float*)d_in[4];   // [Is,H]
  const float* eguw = (const float*)d_in[5];   // [E,H,2I]
  const float* edw  = (const float*)d_in[6];   // [E,I,H]
  float* out = (float*)d_out;                  // [T,H]

  char* ws = (char*)d_ws;
  int*   counts   = (int*)(ws + 0);
  int*   etok     = (int*)(ws + 4096);
  float* ew       = (float*)(ws + 4096 + 131072);
  float* gate_tok = (float*)(ws + 4096 + 2*131072);
  float* logits   = (float*)(ws + (512u<<10));          // 512 KB
  _Float16* plane = (_Float16*)(ws + (1u<<20));         // 8 MiB, reused ACT -> ACTG

  hipMemsetAsync(counts, 0, E_NUM*sizeof(int), stream);
  k_logits<<<T_TOK/32, 256, 0, stream>>>(x, gw, sgw, logits, gate_tok);
  k_topk<<<T_TOK/4, 256, 0, stream>>>(logits, counts, etok, ew);
  k_gu_shared<<<dim3(IS_DIM/64, T_TOK/128), 256, 0, stream>>>(x, sguw, plane);
  k_dn_shared<<<dim3(H_DIM/128, T_TOK/128), 256, 0, stream>>>(plane, sdw, gate_tok, out);
  for (int g = 0; g < 4; ++g) {
    k_gu_expert<<<dim3(I_DIM/64, CAP/128, 16), 256, 0, stream>>>(x, eguw, counts, etok, plane, g*16);
    k_dn_expert<<<dim3(H_DIM/128, CAP/128, 16), 256, 0, stream>>>(plane, edw, counts, etok, ew, out, g*16);
  }
}

// Round 5
// 968.747 us; speedup vs baseline: 2.1960x; 1.2170x over previous
//
#include <hip/hip_runtime.h>
#include <math.h>

#define T_TOK 2048
#define H_DIM 1024
#define E_NUM 64
#define KTOP 8
#define CAP  512
#define I_DIM 512
#define IS_DIM 2048

#define LDSTR 40   // padded LDS row stride in fp16 elems (80 B)

typedef __attribute__((ext_vector_type(8))) _Float16 half8;
typedef __attribute__((ext_vector_type(4))) _Float16 half4v;
typedef __attribute__((ext_vector_type(4))) float f32x4;

__device__ __forceinline__ float sigm(float x){ return 1.f/(1.f+__expf(-x)); }

// ---------------- weight fp32[K,N] -> fp16[N,K] transpose-convert (batched) ----------------
__global__ __launch_bounds__(256)
void k_tcvt(const float* __restrict__ S, _Float16* __restrict__ D, int K, int N)
{
  __shared__ float T[64][65];
  const size_t so = (size_t)blockIdx.z*K*N;
  const int n0 = blockIdx.x*64, k0 = blockIdx.y*64;
  const int tid = threadIdx.x;
  #pragma unroll
  for (int i=0;i<4;++i){
    int id = tid + i*256;
    int r = id >> 4, c = (id & 15)*4;
    float4 v = *(const float4*)(S + so + (size_t)(k0+r)*N + n0 + c);
    T[r][c]=v.x; T[r][c+1]=v.y; T[r][c+2]=v.z; T[r][c+3]=v.w;
  }
  __syncthreads();
  #pragma unroll
  for (int i=0;i<2;++i){
    int id = tid + i*256;
    int n = id >> 3, kc = (id & 7)*8;
    half8 h;
    #pragma unroll
    for (int j=0;j<8;++j) h[j] = (_Float16)T[kc+j][n];
    *(half8*)(D + so + (size_t)(n0+n)*K + k0 + kc) = h;
  }
}

// ---------------- X fp32 -> fp16 ----------------
__global__ __launch_bounds__(256)
void k_cvtx(const float* __restrict__ X, _Float16* __restrict__ Xh)
{
  size_t i = ((size_t)blockIdx.x*256 + threadIdx.x)*4;
  float4 v = *(const float4*)(X + i);
  half4v h = { (_Float16)v.x, (_Float16)v.y, (_Float16)v.z, (_Float16)v.w };
  *(half4v*)(Xh + i) = h;
}

// ---------------- router part 1: logits = X @ GW (fp32, exact routing) + token gate ----------------
__global__ __launch_bounds__(256)
void k_logits(const float* __restrict__ X, const float* __restrict__ GW,
              const float* __restrict__ SGW, float* __restrict__ logits,
              float* __restrict__ gate_tok)
{
  __shared__ float Xs[32*33];
  __shared__ float Ws[32*64];
  __shared__ float SGWs[32];
  __shared__ float red[256];
  const int tid = threadIdx.x;
  const int t0 = blockIdx.x * 32;
  const int tx = tid & 15, ty = tid >> 4;
  const int tg = tid & 31, qq = tid >> 5;
  float acc[2][4] = {};
  float gacc = 0.f;

  for (int k0 = 0; k0 < H_DIM; k0 += 32) {
    {
      int row = tid >> 3, c4 = (tid & 7)*4;
      float4 v = *(const float4*)(X + (size_t)(t0+row)*H_DIM + k0 + c4);
      Xs[row*33+c4+0]=v.x; Xs[row*33+c4+1]=v.y; Xs[row*33+c4+2]=v.z; Xs[row*33+c4+3]=v.w;
    }
    #pragma unroll
    for (int i=0;i<2;++i){
      int id = tid + i*256;
      int kk = id >> 4, c4 = (id & 15)*4;
      *(float4*)(Ws + kk*64 + c4) = *(const float4*)(GW + (size_t)(k0+kk)*E_NUM + c4);
    }
    if (tid < 32) SGWs[tid] = SGW[k0 + tid];
    __syncthreads();
    #pragma unroll 8
    for (int k=0;k<32;++k){
      float b[4];
      #pragma unroll
      for(int j=0;j<4;++j) b[j] = Ws[k*64 + tx*4 + j];
      #pragma unroll
      for(int i=0;i<2;++i){
        float a = Xs[(ty*2+i)*33 + k];
        #pragma unroll
        for(int j=0;j<4;++j) acc[i][j] = fmaf(a, b[j], acc[i][j]);
      }
    }
    #pragma unroll
    for (int k=0;k<4;++k)
      gacc = fmaf(Xs[tg*33 + qq*4 + k], SGWs[qq*4+k], gacc);
    __syncthreads();
  }
  #pragma unroll
  for(int i=0;i<2;++i){
    float4 o = {acc[i][0],acc[i][1],acc[i][2],acc[i][3]};
    *(float4*)(logits + (size_t)(t0+ty*2+i)*E_NUM + tx*4) = o;
  }
  red[tid] = gacc; __syncthreads();
  if (tid < 32) {
    float g = 0.f;
    #pragma unroll
    for (int p=0;p<8;++p) g += red[tid + p*32];
    gate_tok[t0+tid] = sigm(g);
  }
}

// ---------------- router part 2: top-8 + softmax-renorm + dispatch ----------------
__global__ __launch_bounds__(256)
void k_topk(const float* __restrict__ logits,
            int* __restrict__ counts, int* __restrict__ etok, float* __restrict__ ew)
{
  const int tid = threadIdx.x;
  const int lane = tid & 63, w = tid >> 6;
  const int t = blockIdx.x*4 + w;
  float curv = logits[(size_t)t*E_NUM + lane];
  int curi = lane;
  float topv[KTOP]; int topi[KTOP];
  #pragma unroll
  for (int r = 0; r < KTOP; ++r) {
    float bv = curv; int bi = curi;
    #pragma unroll
    for (int off = 32; off > 0; off >>= 1) {
      float ov = __shfl_xor(bv, off);
      int oi = __shfl_xor(bi, off);
      if (ov > bv || (ov == bv && oi < bi)) { bv = ov; bi = oi; }
    }
    topv[r] = bv; topi[r] = bi;
    if (curi == bi) curv = -INFINITY;
  }
  if (lane == 0) {
    float m = topv[0], s = 0.f, wv[KTOP];
    #pragma unroll
    for (int r = 0; r < KTOP; ++r){ wv[r] = __expf(topv[r]-m); s += wv[r]; }
    float inv = 1.f/s;
    for (int r = 0; r < KTOP; ++r) {
      int ee = topi[r];
      int pos = atomicAdd(&counts[ee], 1);
      if (pos < CAP) {
        etok[ee*CAP + pos] = t;
        ew[ee*CAP + pos] = wv[r]*inv;
      }
    }
  }
}

// ---------------- MFMA engine (fp16 weights pre-transposed [N,K]) ----------------
// A tile [128m x 32k], B tile [128n x 32k]; both staged as half8 copies.
// B LDS rows chunk-XOR swizzled: logical 8-elem chunk c at slot c ^ ((n>>3)&3).

__device__ __forceinline__ void loadA2(const _Float16* __restrict__ base, int ldk, int k0,
                                       int tid, half8 r[2]) {
  #pragma unroll
  for (int i=0;i<2;++i){
    int id = tid + i*256;
    int m = id >> 2, kc = (id & 3)*8;
    r[i] = *(const half8*)(base + (size_t)m*ldk + k0 + kc);
  }
}
__device__ __forceinline__ void storeA(_Float16* As, int tid, const half8 r[2]) {
  #pragma unroll
  for (int i=0;i<2;++i){
    int id = tid + i*256;
    int m = id >> 2, kc = (id & 3)*8;
    *(half8*)(As + m*LDSTR + kc) = r[i];
  }
}
__device__ __forceinline__ void loadB2(const _Float16* __restrict__ Bt, int ldk,
                                       int r0, int r1, int k0, int tid, half8 r[2]) {
  #pragma unroll
  for (int i=0;i<2;++i){
    int id = tid + i*256;
    int n = id >> 2, kc = (id & 3)*8;
    int grow = (n < 64) ? (r0 + n) : (r1 + n - 64);
    r[i] = *(const half8*)(Bt + (size_t)grow*ldk + k0 + kc);
  }
}
__device__ __forceinline__ void storeB(_Float16* Bs, int tid, const half8 r[2]) {
  #pragma unroll
  for (int i=0;i<2;++i){
    int id = tid + i*256;
    int n = id >> 2, c = id & 3;
    *(half8*)(Bs + n*LDSTR + ((c ^ ((n>>3)&3))*8)) = r[i];
  }
}

__device__ __forceinline__ void mfma_tiles_h(const _Float16* As, const _Float16* Bs,
                                             int wy, const int* bidx, int lane, f32x4 acc[4][4])
{
  const int lm = lane & 15, q = lane >> 4;
  half8 a[4];
  #pragma unroll
  for (int mt = 0; mt < 4; ++mt)
    a[mt] = *(const half8*)(As + (wy*64 + mt*16 + lm)*LDSTR + q*8);
  #pragma unroll
  for (int nt = 0; nt < 4; ++nt) {
    int n = bidx[nt]*16 + lm;
    half8 b = *(const half8*)(Bs + n*LDSTR + ((q ^ ((n>>3)&3))*8));
    #pragma unroll
    for (int mt = 0; mt < 4; ++mt)
      acc[mt][nt] = __builtin_amdgcn_mfma_f32_16x16x32_f16(a[mt], b, acc[mt][nt], 0,0,0);
  }
}

#define DECL_LDS \
  __shared__ __align__(16) _Float16 As[128*LDSTR]; \
  __shared__ __align__(16) _Float16 Bs[128*LDSTR];

#define ZERO_ACC \
  f32x4 acc[4][4]; \
  _Pragma("unroll") for (int a_=0;a_<4;++a_) _Pragma("unroll") for (int b_=0;b_<4;++b_) \
    acc[a_][b_] = (f32x4){0.f,0.f,0.f,0.f};

// ---------------- shared gate_up + SwiGLU -> ACT fp16 [T, IS] ----------------
__global__ __launch_bounds__(256,3)
void k_gu_shared(const _Float16* __restrict__ Xh, const _Float16* __restrict__ Wt,
                 _Float16* __restrict__ O)
{
  DECL_LDS
  const int tid = threadIdx.x, lane = tid & 63, wave = tid >> 6;
  const int wx = wave & 1, wy = wave >> 1;
  const int m0 = blockIdx.y * 128;
  const int gn0 = blockIdx.x * 64;
  ZERO_ACC
  const int bidx[4] = {2*wx, 2*wx+1, 4+2*wx, 5+2*wx};
  const _Float16* Ab = Xh + (size_t)m0*H_DIM;

  half8 ra[2], rb[2];
  loadA2(Ab, H_DIM, 0, tid, ra);
  loadB2(Wt, H_DIM, gn0, IS_DIM + gn0, 0, tid, rb);
  for (int k0 = 0; k0 < H_DIM; k0 += 32) {
    storeA(As, tid, ra); storeB(Bs, tid, rb);
    __syncthreads();
    if (k0 + 32 < H_DIM) {
      loadA2(Ab, H_DIM, k0+32, tid, ra);
      loadB2(Wt, H_DIM, gn0, IS_DIM + gn0, k0+32, tid, rb);
    }
    mfma_tiles_h(As, Bs, wy, bidx, lane, acc);
    __syncthreads();
  }
  const int lm = lane & 15, q = lane >> 4;
  #pragma unroll
  for (int mt = 0; mt < 4; ++mt) {
    int m = m0 + wy*64 + mt*16 + q*4;
    #pragma unroll
    for (int jj = 0; jj < 2; ++jj) {
      int col = gn0 + (2*wx + jj)*16 + lm;
      #pragma unroll
      for (int r = 0; r < 4; ++r) {
        float g = acc[mt][jj][r], u = acc[mt][2+jj][r];
        O[(size_t)(m + r)*IS_DIM + col] = (_Float16)(g * sigm(g) * u);
      }
    }
  }
}

// ---------------- shared down proj * token gate -> OUT ----------------
__global__ __launch_bounds__(256,3)
void k_dn_shared(const _Float16* __restrict__ S, const _Float16* __restrict__ Wt,
                 const float* __restrict__ gate_tok, float* __restrict__ OUT)
{
  DECL_LDS
  const int tid = threadIdx.x, lane = tid & 63, wave = tid >> 6;
  const int wx = wave & 1, wy = wave >> 1;
  const int m0 = blockIdx.y * 128;
  const int n0 = blockIdx.x * 128;
  ZERO_ACC
  const int bidx[4] = {4*wx, 4*wx+1, 4*wx+2, 4*wx+3};
  const _Float16* Ab = S + (size_t)m0*IS_DIM;

  half8 ra[2], rb[2];
  loadA2(Ab, IS_DIM, 0, tid, ra);
  loadB2(Wt, IS_DIM, n0, n0 + 64, 0, tid, rb);
  for (int k0 = 0; k0 < IS_DIM; k0 += 32) {
    storeA(As, tid, ra); storeB(Bs, tid, rb);
    __syncthreads();
    if (k0 + 32 < IS_DIM) {
      loadA2(Ab, IS_DIM, k0+32, tid, ra);
      loadB2(Wt, IS_DIM, n0, n0 + 64, k0+32, tid, rb);
    }
    mfma_tiles_h(As, Bs, wy, bidx, lane, acc);
    __syncthreads();
  }
  const int lm = lane & 15, q = lane >> 4;
  #pragma unroll
  for (int mt = 0; mt < 4; ++mt) {
    int m = m0 + wy*64 + mt*16 + q*4;
    #pragma unroll
    for (int r = 0; r < 4; ++r) {
      float gt = gate_tok[m + r];
      #pragma unroll
      for (int nt = 0; nt < 4; ++nt) {
        int col = n0 + wx*64 + nt*16 + lm;
        OUT[(size_t)(m + r)*H_DIM + col] = acc[mt][nt][r] * gt;
      }
    }
  }
}

// ---------------- expert gate_up + SwiGLU -> ACTG fp16 [16, CAP, I] ----------------
__global__ __launch_bounds__(256,3)
void k_gu_expert(const _Float16* __restrict__ Xh, const _Float16* __restrict__ Wt,
                 const int* __restrict__ counts, const int* __restrict__ etok,
                 _Float16* __restrict__ O, int e_base)
{
  const int el = blockIdx.z, e = e_base + el;
  int cnt = counts[e]; if (cnt > CAP) cnt = CAP;
  const int m0 = blockIdx.y * 128;
  if (m0 >= cnt) return;
  const int gn0 = blockIdx.x * 64;
  DECL_LDS
  const int tid = threadIdx.x, lane = tid & 63, wave = tid >> 6;
  const int wx = wave & 1, wy = wave >> 1;
  ZERO_ACC
  const int bidx[4] = {2*wx, 2*wx+1, 4+2*wx, 5+2*wx};
  const _Float16* Wb = Wt + (size_t)e*H_DIM*(2*I_DIM);

  int t2[2];
  #pragma unroll
  for (int i = 0; i < 2; ++i) {
    int m = m0 + ((tid + i*256) >> 2);
    t2[i] = (m < cnt) ? etok[e*CAP + m] : -1;
  }

  half8 ra[2], rb[2];
  #pragma unroll
  for (int i=0;i<2;++i){
    int kc = ((tid + i*256) & 3)*8;
    ra[i] = (t2[i] >= 0) ? *(const half8*)(Xh + (size_t)t2[i]*H_DIM + kc)
                         : (half8){0,0,0,0,0,0,0,0};
  }
  loadB2(Wb, H_DIM, gn0, I_DIM + gn0, 0, tid, rb);
  for (int k0 = 0; k0 < H_DIM; k0 += 32) {
    storeA(As, tid, ra); storeB(Bs, tid, rb);
    __syncthreads();
    if (k0 + 32 < H_DIM) {
      #pragma unroll
      for (int i=0;i<2;++i){
        int kc = ((tid + i*256) & 3)*8;
        ra[i] = (t2[i] >= 0) ? *(const half8*)(Xh + (size_t)t2[i]*H_DIM + k0 + 32 + kc)
                             : (half8){0,0,0,0,0,0,0,0};
      }
      loadB2(Wb, H_DIM, gn0, I_DIM + gn0, k0+32, tid, rb);
    }
    mfma_tiles_h(As, Bs, wy, bidx, lane, acc);
    __syncthreads();
  }
  const int lm = lane & 15, q = lane >> 4;
  #pragma unroll
  for (int mt = 0; mt < 4; ++mt) {
    int m = m0 + wy*64 + mt*16 + q*4;
    #pragma unroll
    for (int jj = 0; jj < 2; ++jj) {
      int col = gn0 + (2*wx + jj)*16 + lm;
      #pragma unroll
      for (int r = 0; r < 4; ++r) {
        if (m + r < cnt) {
          float g = acc[mt][jj][r], u = acc[mt][2+jj][r];
          O[((size_t)el*CAP + m + r)*I_DIM + col] = (_Float16)(g * sigm(g) * u);
        }
      }
    }
  }
}

// ---------------- expert down proj -> atomicAdd into OUT ----------------
__global__ __launch_bounds__(256,3)
void k_dn_expert(const _Float16* __restrict__ G, const _Float16* __restrict__ Wt,
                 const int* __restrict__ counts, const int* __restrict__ etok,
                 const float* __restrict__ ew, float* __restrict__ OUT, int e_base)
{
  const int el = blockIdx.z, e = e_base + el;
  int cnt = counts[e]; if (cnt > CAP) cnt = CAP;
  const int m0 = blockIdx.y * 128;
  if (m0 >= cnt) return;
  const int n0 = blockIdx.x * 128;
  DECL_LDS
  const int tid = threadIdx.x, lane = tid & 63, wave = tid >> 6;
  const int wx = wave & 1, wy = wave >> 1;
  ZERO_ACC
  const int bidx[4] = {4*wx, 4*wx+1, 4*wx+2, 4*wx+3};
  const _Float16* Wb = Wt + (size_t)e*I_DIM*H_DIM;
  const _Float16* Ab = G + ((size_t)el*CAP + m0)*I_DIM;

  bool ok2[2];
  #pragma unroll
  for (int i=0;i<2;++i) ok2[i] = (m0 + ((tid + i*256) >> 2)) < cnt;

  half8 ra[2], rb[2];
  #pragma unroll
  for (int i=0;i<2;++i){
    int id = tid + i*256;
    int m = id >> 2, kc = (id & 3)*8;
    ra[i] = ok2[i] ? *(const half8*)(Ab + (size_t)m*I_DIM + kc) : (half8){0,0,0,0,0,0,0,0};
  }
  loadB2(Wb, I_DIM, n0, n0 + 64, 0, tid, rb);
  for (int k0 = 0; k0 < I_DIM; k0 += 32) {
    storeA(As, tid, ra); storeB(Bs, tid, rb);
    __syncthreads();
    if (k0 + 32 < I_DIM) {
      #pragma unroll
      for (int i=0;i<2;++i){
        int id = tid + i*256;
        int m = id >> 2, kc = (id & 3)*8;
        ra[i] = ok2[i] ? *(const half8*)(Ab + (size_t)m*I_DIM + k0 + 32 + kc) : (half8){0,0,0,0,0,0,0,0};
      }
      loadB2(Wb, I_DIM, n0, n0 + 64, k0+32, tid, rb);
    }
    mfma_tiles_h(As, Bs, wy, bidx, lane, acc);
    __syncthreads();
  }
  const int lm = lane & 15, q = lane >> 4;
  #pragma unroll
  for (int mt = 0; mt < 4; ++mt) {
    int m = m0 + wy*64 + mt*16 + q*4;
    #pragma unroll
    for (int r = 0; r < 4; ++r) {
      if (m + r < cnt) {
        float w = ew[e*CAP + m + r];
        int tok = etok[e*CAP + m + r];
        float* op = OUT + (size_t)tok*H_DIM;
        #pragma unroll
        for (int nt = 0; nt < 4; ++nt) {
          int col = n0 + wx*64 + nt*16 + lm;
          atomicAdd(op + col, acc[mt][nt][r] * w);
        }
      }
    }
  }
}

extern "C" void kernel_launch(void* const* d_in, const int* in_sizes, int n_in,
                              void* d_out, int out_size, void* d_ws, size_t ws_size,
                              hipStream_t stream) {
  const float* x    = (const float*)d_in[0];   // [T,H]
  const float* gw   = (const float*)d_in[1];   // [H,E]
  const float* sgw  = (const float*)d_in[2];   // [H,1]
  const float* sguw = (const float*)d_in[3];   // [H,2*Is]
  const float* sdw  = (const float*)d_in[4];   // [Is,H]
  const float* eguw = (const float*)d_in[5];   // [E,H,2I]
  const float* edw  = (const float*)d_in[6];   // [E,I,H]
  float* out = (float*)d_out;                  // [T,H]

  char* ws = (char*)d_ws;
  int*   counts   = (int*)(ws + 0);
  int*   etok     = (int*)(ws + 4096);
  float* ew       = (float*)(ws + 4096 + 131072);
  float* gate_tok = (float*)(ws + 4096 + 2*131072);
  float* logits   = (float*)(ws + (512u<<10));           // 512 KB
  _Float16* plane  = (_Float16*)(ws + (1u<<20));         // 8 MiB: ACT -> ACTG (reused)
  _Float16* Xh     = (_Float16*)(ws + (16u<<20));        // 4 MiB
  _Float16* sguwT  = (_Float16*)(ws + (24u<<20));        // 8 MiB  [2IS, H]
  _Float16* sdwT   = (_Float16*)(ws + (32u<<20));        // 4 MiB  [H, IS]
  _Float16* eguwT  = (_Float16*)(ws + (40u<<20));        // 128 MiB [E][2I, H]
  _Float16* edwT   = (_Float16*)(ws + (168u<<20));       // 64 MiB  [E][H, I]

  hipMemsetAsync(counts, 0, E_NUM*sizeof(int), stream);
  k_cvtx<<<T_TOK*H_DIM/1024, 256, 0, stream>>>(x, Xh);
  k_tcvt<<<dim3(4096/64, 1024/64, 1),  256, 0, stream>>>(sguw, sguwT, 1024, 4096);
  k_tcvt<<<dim3(1024/64, 2048/64, 1),  256, 0, stream>>>(sdw,  sdwT,  2048, 1024);
  k_tcvt<<<dim3(1024/64, 1024/64, 64), 256, 0, stream>>>(eguw, eguwT, 1024, 1024);
  k_tcvt<<<dim3(1024/64,  512/64, 64), 256, 0, stream>>>(edw,  edwT,   512, 1024);
  k_logits<<<T_TOK/32, 256, 0, stream>>>(x, gw, sgw, logits, gate_tok);
  k_topk<<<T_TOK/4, 256, 0, stream>>>(logits, counts, etok, ew);
  k_gu_shared<<<dim3(IS_DIM/64, T_TOK/128), 256, 0, stream>>>(Xh, sguwT, plane);
  k_dn_shared<<<dim3(H_DIM/128, T_TOK/128), 256, 0, stream>>>(plane, sdwT, gate_tok, out);
  for (int g = 0; g < 4; ++g) {
    k_gu_expert<<<dim3(I_DIM/64, CAP/128, 16), 256, 0, stream>>>(Xh, eguwT, counts, etok, plane, g*16);
    k_dn_expert<<<dim3(H_DIM/128, CAP/128, 16), 256, 0, stream>>>(plane, edwT, counts, etok, ew, out, g*16);
  }
}